// Round 1
// baseline (403.358 us; speedup 1.0000x reference)
//
#include <hip/hip_runtime.h>
#include <hip/hip_bf16.h>

typedef __hip_bfloat16 bf16;
typedef float f32x4 __attribute__((ext_vector_type(4)));
typedef float fvec4 __attribute__((ext_vector_type(4)));
typedef short s16x8 __attribute__((ext_vector_type(8)));

#define NB_B 2
#define NB_S 2048
#define NB_E 1024
#define NB_H 16
#define NB_D 64

typedef const __attribute__((address_space(1))) void* GPTR;
typedef __attribute__((address_space(3))) void* LPTR;

__device__ __forceinline__ void gld16(const void* g, void* l) {
  __builtin_amdgcn_global_load_lds((GPTR)g, (LPTR)l, 16, 0, 0);
}

__device__ __forceinline__ s16x8 ld8(const bf16* p) { return *(const s16x8*)p; }

__device__ __forceinline__ f32x4 MFMA(s16x8 a, s16x8 b, f32x4 c) {
  return __builtin_amdgcn_mfma_f32_16x16x32_bf16(a, b, c, 0, 0, 0);
}

// ---------------- f32 -> bf16 convert ----------------
struct __align__(8) bf16x4 { bf16 a, b, c, d; };

__global__ void cvt_kernel(const float* __restrict__ in, bf16* __restrict__ out, int n4) {
  int i = blockIdx.x * blockDim.x + threadIdx.x;
  if (i >= n4) return;
  fvec4 v = ((const fvec4*)in)[i];
  bf16x4 o = { bf16(v.x), bf16(v.y), bf16(v.z), bf16(v.w) };
  ((bf16x4*)out)[i] = o;
}

// ---------------- lambda scalar ----------------
__global__ void lam_kernel(const float* lq1, const float* lq2,
                           const float* lk1, const float* lk2, float* out) {
  int l = threadIdx.x;  // 64 threads
  float d1 = lq1[l] * lk1[l];
  float d2 = lq2[l] * lk2[l];
#pragma unroll
  for (int o = 32; o; o >>= 1) { d1 += __shfl_xor(d1, o); d2 += __shfl_xor(d2, o); }
  if (l == 0) out[0] = expf(d1) - expf(d2) + 0.8f;
}

// ---------------- GEMM: C = A @ B^T,  A[M][K] bf16, B[N][K] bf16 ----------------
// EPI 0: bf16 out to [b][h][s][128]   (Q/K proj, N=2048)
// EPI 1: bf16 out to [b][h][d][s]     (V proj transposed, N=1024)
// EPI 2: f32 out row-major ld=1024    (final out proj)
template <int EPI>
__global__ __launch_bounds__(256) void gemm_bt(const bf16* __restrict__ A,
                                               const bf16* __restrict__ Bw,
                                               bf16* __restrict__ Ob,
                                               float* __restrict__ Of,
                                               int Kd, float oscale) {
  __shared__ bf16 As[128 * 32];
  __shared__ bf16 Bs[128 * 32];
  const int tid = threadIdx.x;
  const int lane = tid & 63;
  const int fr = lane & 15, fq = lane >> 4;
  const int wave = tid >> 6;
  const int wr = (wave >> 1) * 64, wc = (wave & 1) * 64;
  const size_t m0 = (size_t)blockIdx.x * 128, n0 = (size_t)blockIdx.y * 128;

  f32x4 acc[4][4];
#pragma unroll
  for (int i = 0; i < 4; i++)
#pragma unroll
    for (int j = 0; j < 4; j++) acc[i][j] = f32x4{0.f, 0.f, 0.f, 0.f};

  const int ca = tid, cb = tid + 256;
  const bf16* ga0 = A + (m0 + (ca >> 2)) * Kd + (ca & 3) * 8;
  const bf16* ga1 = A + (m0 + (cb >> 2)) * Kd + (cb & 3) * 8;
  const bf16* gb0 = Bw + (n0 + (ca >> 2)) * Kd + (ca & 3) * 8;
  const bf16* gb1 = Bw + (n0 + (cb >> 2)) * Kd + (cb & 3) * 8;
  bf16* la0 = As + ca * 8; bf16* la1 = As + cb * 8;
  bf16* lb0 = Bs + ca * 8; bf16* lb1 = Bs + cb * 8;

  for (int kt = 0; kt < Kd; kt += 32) {
    __syncthreads();  // previous iteration's LDS reads complete
    gld16(ga0 + kt, la0);
    gld16(ga1 + kt, la1);
    gld16(gb0 + kt, lb0);
    gld16(gb1 + kt, lb1);
    __syncthreads();  // staging drained (vmcnt(0) before barrier)

    s16x8 af[4], bfv[4];
#pragma unroll
    for (int mi = 0; mi < 4; mi++) af[mi] = ld8(&As[(wr + mi * 16 + fr) * 32 + fq * 8]);
#pragma unroll
    for (int ni = 0; ni < 4; ni++) bfv[ni] = ld8(&Bs[(wc + ni * 16 + fr) * 32 + fq * 8]);
#pragma unroll
    for (int mi = 0; mi < 4; mi++)
#pragma unroll
      for (int ni = 0; ni < 4; ni++)
        acc[mi][ni] = MFMA(af[mi], bfv[ni], acc[mi][ni]);
  }

  // epilogue: C row = fq*4+i, col = fr within each 16x16 fragment
#pragma unroll
  for (int mi = 0; mi < 4; mi++)
#pragma unroll
    for (int ni = 0; ni < 4; ni++)
#pragma unroll
      for (int i = 0; i < 4; i++) {
        size_t m = m0 + wr + mi * 16 + fq * 4 + i;
        size_t n = n0 + wc + ni * 16 + fr;
        float v = acc[mi][ni][i] * oscale;
        if constexpr (EPI == 0) {
          size_t b = m >> 11, s = m & 2047, h = n >> 7, dd = n & 127;
          Ob[((b * NB_H + h) * NB_S + s) * 128 + dd] = bf16(v);
        } else if constexpr (EPI == 1) {
          size_t b = m >> 11, s = m & 2047, h = n >> 6, d = n & 63;
          Ob[((b * NB_H + h) * NB_D + d) * NB_S + s] = bf16(v);
        } else {
          Of[m * 1024 + n] = v;
        }
      }
}

// ---------------- fused causal differential flash attention ----------------
// Q: [b][h][s][128] bf16 (first 64 = Q1*0.125*log2e, last 64 = Q2*0.125*log2e)
// K: same layout (unscaled). Vt: [b][h][d][s] bf16.  X out: [b][h][s][64] f32.
__global__ __launch_bounds__(256) void attn_kernel(
    const bf16* __restrict__ Q, const bf16* __restrict__ Kk, const bf16* __restrict__ Vt,
    const int* __restrict__ tok, const float* __restrict__ amask,
    const float* __restrict__ lamp, float* __restrict__ X) {
  __shared__ bf16 K1s[64 * 64];
  __shared__ bf16 K2s[64 * 64];
  __shared__ bf16 Vts[64 * 64];
  __shared__ bf16 Ps[4][2][16 * 64];  // per-wave P scratch (swizzled)

  const int tid = threadIdx.x, lane = tid & 63, wave = tid >> 6;
  const int fr = lane & 15, fq = lane >> 4;
  const int bh = blockIdx.y, b = bh >> 4, h = bh & 15;
  const int q0 = blockIdx.x * 64;
  const int qw = q0 + wave * 16;

  const float lam = lamp[0];
  const float L2E = 1.44269504088896340736f;
  const float slopeL = exp2f(-0.5f * (float)(h + 1)) * L2E;

  // Q fragments (A-layout: row = fr, k = fq*8.. within each 32-k block)
  const bf16* qrow = Q + ((size_t)bh * NB_S + qw + fr) * 128;
  s16x8 q1[2], q2[2];
  q1[0] = ld8(qrow + fq * 8);       q1[1] = ld8(qrow + 32 + fq * 8);
  q2[0] = ld8(qrow + 64 + fq * 8);  q2[1] = ld8(qrow + 96 + fq * 8);

  float pqs[4]; int qg[4];
#pragma unroll
  for (int i = 0; i < 4; i++) {
    qg[i] = qw + fq * 4 + i;
    pqs[i] = slopeL * (float)tok[b * NB_S + qg[i]];
  }

  float m1[4], l1[4], m2[4], l2[4];
  f32x4 acc1[4], acc2[4];
#pragma unroll
  for (int i = 0; i < 4; i++) { m1[i] = m2[i] = -1e30f; l1[i] = l2[i] = 0.f; }
#pragma unroll
  for (int nt = 0; nt < 4; nt++) { acc1[nt] = f32x4{0.f,0.f,0.f,0.f}; acc2[nt] = f32x4{0.f,0.f,0.f,0.f}; }

  const bf16* Kbase = Kk + (size_t)bh * NB_S * 128;
  const bf16* Vbase = Vt + (size_t)bh * NB_D * NB_S;

  // staging descriptors: 1536 16B chunks (K1 512 | K2 512 | Vt 512), 6 per thread.
  // LDS dest linear; XOR swizzle applied on the GLOBAL source (rule #21).
  const bf16* gsrc[6]; bf16* ldst[6]; int gstr[6];
#pragma unroll
  for (int i = 0; i < 6; i++) {
    int c = tid + i * 256, seg = c >> 9, cc = c & 511;
    int row = cc >> 3, col8 = cc & 7, sc = col8 ^ (row & 7);
    ldst[i] = (seg == 0 ? K1s : (seg == 1 ? K2s : Vts)) + cc * 8;
    if (seg == 2) { gsrc[i] = Vbase + (size_t)row * NB_S + sc * 8; gstr[i] = 1; }
    else          { gsrc[i] = Kbase + (size_t)row * 128 + seg * 64 + sc * 8; gstr[i] = 128; }
  }

  const int ntiles = q0 / 64 + 1;
  for (int t = 0; t < ntiles; ++t) {
    const int kv0 = t * 64;
    __syncthreads();
#pragma unroll
    for (int i = 0; i < 6; i++) gld16(gsrc[i] + (size_t)kv0 * gstr[i], ldst[i]);
    __syncthreads();

    // ---- QK^T for both score sets ----
    f32x4 c1[4], c2[4];
#pragma unroll
    for (int nt = 0; nt < 4; nt++) { c1[nt] = f32x4{0.f,0.f,0.f,0.f}; c2[nt] = f32x4{0.f,0.f,0.f,0.f}; }
#pragma unroll
    for (int nt = 0; nt < 4; nt++) {
      const int crow = nt * 16 + fr;
#pragma unroll
      for (int kk = 0; kk < 2; kk++) {
        const int sch = ((kk * 4 + fq) ^ (crow & 7)) * 8;
        c1[nt] = MFMA(q1[kk], ld8(&K1s[crow * 64 + sch]), c1[nt]);
        c2[nt] = MFMA(q2[kk], ld8(&K2s[crow * 64 + sch]), c2[nt]);
      }
    }

    // ---- bias / masks (log2 domain) ----
    float pks[4], padv[4]; int kg[4];
#pragma unroll
    for (int nt = 0; nt < 4; nt++) {
      kg[nt] = kv0 + nt * 16 + fr;
      pks[nt] = slopeL * (float)tok[b * NB_S + kg[nt]];
      padv[nt] = (amask[b * NB_S + kg[nt]] - 1.f) * 1.44269504e9f;
    }

    float sv1[4][4], sv2[4][4];
#pragma unroll
    for (int nt = 0; nt < 4; nt++)
#pragma unroll
      for (int i = 0; i < 4; i++) {
        const float biasv = pks[nt] - pqs[i] + padv[nt];
        const bool dead = kg[nt] > qg[i];
        sv1[nt][i] = dead ? -1e30f : c1[nt][i] + biasv;
        sv2[nt][i] = dead ? -1e30f : c2[nt][i] + biasv;
      }

    // ---- online softmax (dual) ----
    float pm1[4], pm2[4];
#pragma unroll
    for (int i = 0; i < 4; i++) {
      pm1[i] = fmaxf(fmaxf(sv1[0][i], sv1[1][i]), fmaxf(sv1[2][i], sv1[3][i]));
      pm2[i] = fmaxf(fmaxf(sv2[0][i], sv2[1][i]), fmaxf(sv2[2][i], sv2[3][i]));
    }
#pragma unroll
    for (int o = 1; o < 16; o <<= 1)
#pragma unroll
      for (int i = 0; i < 4; i++) {
        pm1[i] = fmaxf(pm1[i], __shfl_xor(pm1[i], o));
        pm2[i] = fmaxf(pm2[i], __shfl_xor(pm2[i], o));
      }
#pragma unroll
    for (int i = 0; i < 4; i++) {
      const float nm1 = fmaxf(m1[i], pm1[i]);
      const float nm2 = fmaxf(m2[i], pm2[i]);
      const float cor1 = exp2f(m1[i] - nm1);
      const float cor2 = exp2f(m2[i] - nm2);
      m1[i] = nm1; m2[i] = nm2;
      float rs1 = 0.f, rs2 = 0.f;
#pragma unroll
      for (int nt = 0; nt < 4; nt++) {
        const float p1 = exp2f(sv1[nt][i] - nm1);
        const float p2 = exp2f(sv2[nt][i] - nm2);
        sv1[nt][i] = p1; sv2[nt][i] = p2;
        rs1 += p1; rs2 += p2;
      }
#pragma unroll
      for (int o = 1; o < 16; o <<= 1) { rs1 += __shfl_xor(rs1, o); rs2 += __shfl_xor(rs2, o); }
      l1[i] = l1[i] * cor1 + rs1;
      l2[i] = l2[i] * cor2 + rs2;
#pragma unroll
      for (int nt = 0; nt < 4; nt++) { acc1[nt][i] *= cor1; acc2[nt][i] *= cor2; }
    }

    // ---- P (C-layout) -> per-wave LDS (swizzled) ----
#pragma unroll
    for (int nt = 0; nt < 4; nt++)
#pragma unroll
      for (int i = 0; i < 4; i++) {
        const int row = fq * 4 + i, cc = nt * 16 + fr;
        const int scc = (cc & 7) | ((((cc >> 3) ^ (row & 7))) << 3);
        Ps[wave][0][row * 64 + scc] = bf16(sv1[nt][i]);
        Ps[wave][1][row * 64 + scc] = bf16(sv2[nt][i]);
      }

    // ---- PV ----
#pragma unroll
    for (int nt = 0; nt < 4; nt++) {
      const int vrow = nt * 16 + fr;
#pragma unroll
      for (int kk = 0; kk < 2; kk++) {
        const int pch = ((kk * 4 + fq) ^ (fr & 7)) * 8;
        const int vch = ((kk * 4 + fq) ^ (vrow & 7)) * 8;
        const s16x8 vf = ld8(&Vts[vrow * 64 + vch]);
        acc1[nt] = MFMA(ld8(&Ps[wave][0][fr * 64 + pch]), vf, acc1[nt]);
        acc2[nt] = MFMA(ld8(&Ps[wave][1][fr * 64 + pch]), vf, acc2[nt]);
      }
    }
  }

  // ---- finalize: out = acc1/l1 - lam * acc2/l2 ----
#pragma unroll
  for (int i = 0; i < 4; i++) { l1[i] = 1.f / l1[i]; l2[i] = lam / l2[i]; }
#pragma unroll
  for (int nt = 0; nt < 4; nt++)
#pragma unroll
    for (int i = 0; i < 4; i++) {
      X[((size_t)bh * NB_S + qw + fq * 4 + i) * NB_D + nt * 16 + fr] =
          acc1[nt][i] * l1[i] - acc2[nt][i] * l2[i];
    }
}

// ---------------- GroupNorm over (b,h): stats then apply ----------------
__global__ __launch_bounds__(256) void gn_part(const float* __restrict__ X, float* __restrict__ part) {
  const int blk = blockIdx.x;  // bh = blk>>3, seg = blk&7
  const int bh = blk >> 3, seg = blk & 7;
  const float* xp = X + (size_t)bh * 131072 + (size_t)seg * 16384;
  float s = 0.f, s2 = 0.f;
  for (int i = threadIdx.x; i < 4096; i += 256) {
    fvec4 v = ((const fvec4*)xp)[i];
    s += v.x + v.y + v.z + v.w;
    s2 += v.x * v.x + v.y * v.y + v.z * v.z + v.w * v.w;
  }
#pragma unroll
  for (int o = 32; o; o >>= 1) { s += __shfl_xor(s, o); s2 += __shfl_xor(s2, o); }
  __shared__ float rs[4], rq[4];
  const int wv = threadIdx.x >> 6, ln = threadIdx.x & 63;
  if (ln == 0) { rs[wv] = s; rq[wv] = s2; }
  __syncthreads();
  if (threadIdx.x == 0) {
    part[blk * 2] = rs[0] + rs[1] + rs[2] + rs[3];
    part[blk * 2 + 1] = rq[0] + rq[1] + rq[2] + rq[3];
  }
}

__global__ __launch_bounds__(256) void gn_apply(const float* __restrict__ X,
                                                const float* __restrict__ part,
                                                const float* __restrict__ gw,
                                                const float* __restrict__ gb,
                                                bf16* __restrict__ Xn) {
  const int blk = blockIdx.x, bh = blk >> 3, seg = blk & 7;
  const int b = bh >> 4, h = bh & 15;
  float s = 0.f, s2 = 0.f;
#pragma unroll
  for (int i = 0; i < 8; i++) { s += part[(bh * 8 + i) * 2]; s2 += part[(bh * 8 + i) * 2 + 1]; }
  const float mean = s * (1.f / 131072.f);
  const float var = s2 * (1.f / 131072.f) - mean * mean;
  const float rstd = rsqrtf(var + 1e-5f) * 0.2f;  // fold (1-LAMBDA_INIT)
  const float* xp = X + (size_t)bh * 131072 + (size_t)seg * 16384;
  for (int i = threadIdx.x; i < 4096; i += 256) {
    fvec4 v = ((const fvec4*)xp)[i];
    const int e = seg * 16384 + i * 4;
    const int srow = e >> 6, d = e & 63;
    const int c = h * 64 + d;
    bf16x4 o = { bf16((v.x - mean) * rstd * gw[c]     + 0.2f * gb[c]),
                 bf16((v.y - mean) * rstd * gw[c + 1] + 0.2f * gb[c + 1]),
                 bf16((v.z - mean) * rstd * gw[c + 2] + 0.2f * gb[c + 2]),
                 bf16((v.w - mean) * rstd * gw[c + 3] + 0.2f * gb[c + 3]) };
    *(bf16x4*)(Xn + ((size_t)b * NB_S + srow) * 1024 + c) = o;
  }
}

// ---------------- launch ----------------
extern "C" void kernel_launch(void* const* d_in, const int* in_sizes, int n_in,
                              void* d_out, int out_size, void* d_ws, size_t ws_size,
                              hipStream_t stream) {
  const float* inputs = (const float*)d_in[0];
  const float* amask  = (const float*)d_in[1];
  const int*   tok    = (const int*)d_in[2];
  const float* Wq = (const float*)d_in[3];
  const float* Wk = (const float*)d_in[4];
  const float* Wv = (const float*)d_in[5];
  const float* Wo = (const float*)d_in[6];
  const float* lq1 = (const float*)d_in[7];
  const float* lq2 = (const float*)d_in[8];
  const float* lk1 = (const float*)d_in[9];
  const float* lk2 = (const float*)d_in[10];
  const float* gw = (const float*)d_in[11];
  const float* gb = (const float*)d_in[12];
  float* out = (float*)d_out;
  char* ws = (char*)d_ws;

  // workspace layout (sequential stream => WAR-safe aliasing):
  // [0, 18.9MB): staging (Xbf|Wqb|Wkb|Wvb), later reused for X (f32, 16.8MB)
  bf16* Xbf = (bf16*)(ws + 0);
  bf16* Wqb = (bf16*)(ws + 8388608);
  bf16* Wkb = (bf16*)(ws + 12582912);
  bf16* Wvb = (bf16*)(ws + 16777216);
  float* X  = (float*)(ws + 0);            // aliases Xbf/Wqb/Wkb (dead by then)
  bf16* Qb  = (bf16*)(ws + 18874368);
  bf16* Xn  = (bf16*)(ws + 18874368);      // aliases Qb (dead after attn)
  bf16* Kb  = (bf16*)(ws + 35651584);
  bf16* Vtb = (bf16*)(ws + 52428800);
  bf16* Wob = (bf16*)(ws + 60817408);
  float* lam = (float*)(ws + 62914560);
  float* gnp = (float*)(ws + 62914816);

  const float QSCALE = 0.125f * 1.44269504088896340736f;  // 1/sqrt(D) * log2(e)

  cvt_kernel<<<4096, 256, 0, stream>>>(inputs, Xbf, 1048576);
  cvt_kernel<<<2048, 256, 0, stream>>>(Wq, Wqb, 524288);
  cvt_kernel<<<2048, 256, 0, stream>>>(Wk, Wkb, 524288);
  cvt_kernel<<<1024, 256, 0, stream>>>(Wv, Wvb, 262144);
  cvt_kernel<<<1024, 256, 0, stream>>>(Wo, Wob, 262144);
  lam_kernel<<<1, 64, 0, stream>>>(lq1, lq2, lk1, lk2, lam);

  gemm_bt<0><<<dim3(32, 16), 256, 0, stream>>>(Xbf, Wqb, Qb, nullptr, 1024, QSCALE);
  gemm_bt<0><<<dim3(32, 16), 256, 0, stream>>>(Xbf, Wkb, Kb, nullptr, 1024, 1.0f);
  gemm_bt<1><<<dim3(32, 8), 256, 0, stream>>>(Xbf, Wvb, Vtb, nullptr, 1024, 1.0f);

  attn_kernel<<<dim3(32, 32), 256, 0, stream>>>(Qb, Kb, Vtb, tok, amask, lam, X);

  gn_part<<<256, 256, 0, stream>>>(X, gnp);
  gn_apply<<<256, 256, 0, stream>>>(X, gnp, gw, gb, Xn);

  gemm_bt<2><<<dim3(32, 8), 256, 0, stream>>>(Xn, Wob, nullptr, out, 1024, 1.0f);
}

// Round 2
// 341.571 us; speedup vs baseline: 1.1809x; 1.1809x over previous
//
#include <hip/hip_runtime.h>
#include <hip/hip_bf16.h>

typedef __hip_bfloat16 bf16;
typedef float f32x4 __attribute__((ext_vector_type(4)));
typedef float fvec4 __attribute__((ext_vector_type(4)));
typedef short s16x8 __attribute__((ext_vector_type(8)));

#define NB_B 2
#define NB_S 2048
#define NB_E 1024
#define NB_H 16
#define NB_D 64

typedef const __attribute__((address_space(1))) void* GPTR;
typedef __attribute__((address_space(3))) void* LPTR;

__device__ __forceinline__ void gld16(const void* g, void* l) {
  __builtin_amdgcn_global_load_lds((GPTR)g, (LPTR)l, 16, 0, 0);
}

__device__ __forceinline__ s16x8 ld8(const bf16* p) { return *(const s16x8*)p; }

__device__ __forceinline__ f32x4 MFMA(s16x8 a, s16x8 b, f32x4 c) {
  return __builtin_amdgcn_mfma_f32_16x16x32_bf16(a, b, c, 0, 0, 0);
}

// ---------------- f32 -> bf16 convert ----------------
struct __align__(8) bf16x4 { bf16 a, b, c, d; };

__global__ void cvt_kernel(const float* __restrict__ in, bf16* __restrict__ out, int n4) {
  int i = blockIdx.x * blockDim.x + threadIdx.x;
  if (i >= n4) return;
  fvec4 v = ((const fvec4*)in)[i];
  bf16x4 o = { bf16(v.x), bf16(v.y), bf16(v.z), bf16(v.w) };
  ((bf16x4*)out)[i] = o;
}

// ---------------- lambda scalar ----------------
__global__ void lam_kernel(const float* lq1, const float* lq2,
                           const float* lk1, const float* lk2, float* out) {
  int l = threadIdx.x;  // 64 threads
  float d1 = lq1[l] * lk1[l];
  float d2 = lq2[l] * lk2[l];
#pragma unroll
  for (int o = 32; o; o >>= 1) { d1 += __shfl_xor(d1, o); d2 += __shfl_xor(d2, o); }
  if (l == 0) out[0] = expf(d1) - expf(d2) + 0.8f;
}

// ---------------- combo bias precompute: combo[h][b][s] = slopeL*tok + padL ----
__global__ void combo_kernel(const int* __restrict__ tok, const float* __restrict__ amask,
                             float* __restrict__ combo) {
  int i = blockIdx.x * 256 + threadIdx.x;  // H*B*S = 65536
  int hh = i >> 12, bs = i & 4095;
  float slopeL = exp2f(-0.5f * (float)(hh + 1)) * 1.44269504088896340736f;
  combo[i] = slopeL * (float)tok[bs] + (amask[bs] - 1.f) * 1.44269504e9f;
}

// ---------------- GEMM: C = A @ B^T (2-phase double-buffered) ----------------
// EPI 0: bf16 out to [b][h][s][128]   (Q/K proj, N=2048)
// EPI 1: bf16 out to [b][h][d][s]     (V proj transposed, N=1024)
// EPI 2: f32 out row-major ld=1024    (final out proj)
template <int EPI>
__global__ __launch_bounds__(256) void gemm_bt(const bf16* __restrict__ A,
                                               const bf16* __restrict__ Bw,
                                               bf16* __restrict__ Ob,
                                               float* __restrict__ Of,
                                               int Kd, float oscale) {
  __shared__ bf16 As[2][128 * 32];
  __shared__ bf16 Bs[2][128 * 32];
  const int tid = threadIdx.x;
  const int lane = tid & 63;
  const int fr = lane & 15, fq = lane >> 4;
  const int wave = tid >> 6;
  const int wr = (wave >> 1) * 64, wc = (wave & 1) * 64;
  const size_t m0 = (size_t)blockIdx.x * 128, n0 = (size_t)blockIdx.y * 128;

  f32x4 acc[4][4];
#pragma unroll
  for (int i = 0; i < 4; i++)
#pragma unroll
    for (int j = 0; j < 4; j++) acc[i][j] = f32x4{0.f, 0.f, 0.f, 0.f};

  const int ca = tid, cb = tid + 256;
  const bf16* ga0 = A + (m0 + (ca >> 2)) * Kd + (ca & 3) * 8;
  const bf16* ga1 = A + (m0 + (cb >> 2)) * Kd + (cb & 3) * 8;
  const bf16* gb0 = Bw + (n0 + (ca >> 2)) * Kd + (ca & 3) * 8;
  const bf16* gb1 = Bw + (n0 + (cb >> 2)) * Kd + (cb & 3) * 8;

  // prologue: stage k-tile 0 into buf 0
  gld16(ga0, &As[0][ca * 8]);
  gld16(ga1, &As[0][cb * 8]);
  gld16(gb0, &Bs[0][ca * 8]);
  gld16(gb1, &Bs[0][cb * 8]);
  __syncthreads();

  const int NKT = Kd >> 5;
  for (int kti = 0; kti < NKT; ++kti) {
    const int cur = kti & 1;
    if (kti + 1 < NKT) {
      const int kt = (kti + 1) << 5;
      gld16(ga0 + kt, &As[cur ^ 1][ca * 8]);
      gld16(ga1 + kt, &As[cur ^ 1][cb * 8]);
      gld16(gb0 + kt, &Bs[cur ^ 1][ca * 8]);
      gld16(gb1 + kt, &Bs[cur ^ 1][cb * 8]);
    }
    s16x8 af[4], bfv[4];
#pragma unroll
    for (int mi = 0; mi < 4; mi++) af[mi] = ld8(&As[cur][(wr + mi * 16 + fr) * 32 + fq * 8]);
#pragma unroll
    for (int ni = 0; ni < 4; ni++) bfv[ni] = ld8(&Bs[cur][(wc + ni * 16 + fr) * 32 + fq * 8]);
#pragma unroll
    for (int mi = 0; mi < 4; mi++)
#pragma unroll
      for (int ni = 0; ni < 4; ni++)
        acc[mi][ni] = MFMA(af[mi], bfv[ni], acc[mi][ni]);
    __syncthreads();
  }

  // epilogue: C row = fq*4+i, col = fr within each 16x16 fragment
#pragma unroll
  for (int mi = 0; mi < 4; mi++)
#pragma unroll
    for (int ni = 0; ni < 4; ni++)
#pragma unroll
      for (int i = 0; i < 4; i++) {
        size_t m = m0 + wr + mi * 16 + fq * 4 + i;
        size_t n = n0 + wc + ni * 16 + fr;
        float v = acc[mi][ni][i] * oscale;
        if constexpr (EPI == 0) {
          size_t b = m >> 11, s = m & 2047, h = n >> 7, dd = n & 127;
          Ob[((b * NB_H + h) * NB_S + s) * 128 + dd] = bf16(v);
        } else if constexpr (EPI == 1) {
          size_t b = m >> 11, s = m & 2047, h = n >> 6, d = n & 63;
          Ob[((b * NB_H + h) * NB_D + d) * NB_S + s] = bf16(v);
        } else {
          Of[m * 1024 + n] = v;
        }
      }
}

// ---------------- fused causal differential flash attention ----------------
// Q/K: [b][h][s][128] bf16 (Q pre-scaled by 0.125*log2e). Vt: [b][h][d][s] bf16.
// combo: [h][b][s] f32 (slope*tok + pad, log2 domain). X out: [b][h][s][64] f32.
// Grid (16, 32): block handles q-blocks {x, 31-x} -> uniform 33 KV tiles/block.
__global__ __launch_bounds__(256) void attn_kernel(
    const bf16* __restrict__ Q, const bf16* __restrict__ Kk, const bf16* __restrict__ Vt,
    const int* __restrict__ tok, const float* __restrict__ combo,
    const float* __restrict__ lamp, float* __restrict__ X) {
  __shared__ bf16 KV[2][3 * 4096];    // per buf: K1(4096) | K2(4096) | Vt(4096)
  __shared__ bf16 Ps[4][2][16 * 64];  // per-wave P scratch (swizzled)

  const int tid = threadIdx.x, lane = tid & 63, wave = tid >> 6;
  const int fr = lane & 15, fq = lane >> 4;
  const int bh = blockIdx.y, b = bh >> 4, h = bh & 15;

  const float lam = lamp[0];
  const float slopeL = exp2f(-0.5f * (float)(h + 1)) * 1.44269504088896340736f;
  const float* comboH = combo + ((size_t)h * NB_B + b) * NB_S;

  const bf16* Kbase = Kk + (size_t)bh * NB_S * 128;
  const bf16* Vbase = Vt + (size_t)bh * NB_D * NB_S;

  // staging: 1536 16B chunks (K1 512 | K2 512 | Vt 512), 6 per thread.
  // LDS dest linear; XOR swizzle applied on the GLOBAL source (rule #21).
  const bf16* gsrc[6]; int gstr[6]; int loff[6];
#pragma unroll
  for (int i = 0; i < 6; i++) {
    int c = tid + i * 256, seg = c >> 9, cc = c & 511;
    int row = cc >> 3, col8 = cc & 7, sc = col8 ^ (row & 7);
    loff[i] = c * 8;
    if (seg == 2) { gsrc[i] = Vbase + (size_t)row * NB_S + sc * 8; gstr[i] = 1; }
    else          { gsrc[i] = Kbase + (size_t)row * 128 + seg * 64 + sc * 8; gstr[i] = 128; }
  }

  for (int qpass = 0; qpass < 2; ++qpass) {
    const int qb = qpass ? (31 - (int)blockIdx.x) : (int)blockIdx.x;
    const int q0 = qb * 64;
    const int qw = q0 + wave * 16;
    const int ntiles = qb + 1;

    // Q fragments (A-layout: row = fr, k chunk = fq within each 32-k block)
    const bf16* qrow = Q + ((size_t)bh * NB_S + qw + fr) * 128;
    s16x8 q1[2], q2[2];
    q1[0] = ld8(qrow + fq * 8);       q1[1] = ld8(qrow + 32 + fq * 8);
    q2[0] = ld8(qrow + 64 + fq * 8);  q2[1] = ld8(qrow + 96 + fq * 8);

    float pqs[4]; int qg[4];
#pragma unroll
    for (int i = 0; i < 4; i++) {
      qg[i] = qw + fq * 4 + i;
      pqs[i] = slopeL * (float)tok[b * NB_S + qg[i]];
    }

    float m1[4], l1[4], m2[4], l2[4];
    f32x4 acc1[4], acc2[4];
#pragma unroll
    for (int i = 0; i < 4; i++) { m1[i] = m2[i] = -1e30f; l1[i] = l2[i] = 0.f; }
#pragma unroll
    for (int nt = 0; nt < 4; nt++) { acc1[nt] = f32x4{0.f,0.f,0.f,0.f}; acc2[nt] = f32x4{0.f,0.f,0.f,0.f}; }

    // prologue: stage tile 0 into buf 0; prefetch combo tile 0
#pragma unroll
    for (int i = 0; i < 6; i++) gld16(gsrc[i], &KV[0][loff[i]]);
    float cmb[4];
#pragma unroll
    for (int nt = 0; nt < 4; nt++) cmb[nt] = comboH[nt * 16 + fr];
    __syncthreads();

    for (int t = 0; t < ntiles; ++t) {
      const int cur = t & 1;
      const int kv0 = t * 64;
      // issue next tile's staging first (overlaps with compute below)
      if (t + 1 < ntiles) {
#pragma unroll
        for (int i = 0; i < 6; i++)
          gld16(gsrc[i] + (size_t)(kv0 + 64) * gstr[i], &KV[cur ^ 1][loff[i]]);
      }
      float cnx[4];
      if (t + 1 < ntiles) {
#pragma unroll
        for (int nt = 0; nt < 4; nt++) cnx[nt] = comboH[kv0 + 64 + nt * 16 + fr];
      }

      const bf16* K1s = &KV[cur][0];
      const bf16* K2s = &KV[cur][4096];
      const bf16* Vts = &KV[cur][8192];

      // ---- QK^T (dual) ----
      f32x4 c1[4], c2[4];
#pragma unroll
      for (int nt = 0; nt < 4; nt++) { c1[nt] = f32x4{0.f,0.f,0.f,0.f}; c2[nt] = f32x4{0.f,0.f,0.f,0.f}; }
#pragma unroll
      for (int nt = 0; nt < 4; nt++) {
        const int crow = nt * 16 + fr;
#pragma unroll
        for (int kk = 0; kk < 2; kk++) {
          const int sch = ((kk * 4 + fq) ^ (crow & 7)) * 8;
          c1[nt] = MFMA(q1[kk], ld8(&K1s[crow * 64 + sch]), c1[nt]);
          c2[nt] = MFMA(q2[kk], ld8(&K2s[crow * 64 + sch]), c2[nt]);
        }
      }

      // ---- bias / mask / dual online softmax (log2 domain) ----
      float sv1[4][4], sv2[4][4];
#pragma unroll
      for (int nt = 0; nt < 4; nt++) {
        const int kg = kv0 + nt * 16 + fr;
#pragma unroll
        for (int i = 0; i < 4; i++) {
          const float biasv = cmb[nt] - pqs[i];
          const bool dead = kg > qg[i];
          sv1[nt][i] = dead ? -1e30f : c1[nt][i] + biasv;
          sv2[nt][i] = dead ? -1e30f : c2[nt][i] + biasv;
        }
      }

      float pm1[4], pm2[4];
#pragma unroll
      for (int i = 0; i < 4; i++) {
        pm1[i] = fmaxf(fmaxf(sv1[0][i], sv1[1][i]), fmaxf(sv1[2][i], sv1[3][i]));
        pm2[i] = fmaxf(fmaxf(sv2[0][i], sv2[1][i]), fmaxf(sv2[2][i], sv2[3][i]));
      }
#pragma unroll
      for (int o = 1; o < 16; o <<= 1)
#pragma unroll
        for (int i = 0; i < 4; i++) {
          pm1[i] = fmaxf(pm1[i], __shfl_xor(pm1[i], o));
          pm2[i] = fmaxf(pm2[i], __shfl_xor(pm2[i], o));
        }
#pragma unroll
      for (int i = 0; i < 4; i++) {
        const float nm1 = fmaxf(m1[i], pm1[i]);
        const float nm2 = fmaxf(m2[i], pm2[i]);
        const float cor1 = exp2f(m1[i] - nm1);
        const float cor2 = exp2f(m2[i] - nm2);
        m1[i] = nm1; m2[i] = nm2;
        float rs1 = 0.f, rs2 = 0.f;
#pragma unroll
        for (int nt = 0; nt < 4; nt++) {
          const float p1 = exp2f(sv1[nt][i] - nm1);
          const float p2 = exp2f(sv2[nt][i] - nm2);
          sv1[nt][i] = p1; sv2[nt][i] = p2;
          rs1 += p1; rs2 += p2;
        }
#pragma unroll
        for (int o = 1; o < 16; o <<= 1) { rs1 += __shfl_xor(rs1, o); rs2 += __shfl_xor(rs2, o); }
        l1[i] = l1[i] * cor1 + rs1;
        l2[i] = l2[i] * cor2 + rs2;
#pragma unroll
        for (int nt = 0; nt < 4; nt++) { acc1[nt][i] *= cor1; acc2[nt][i] *= cor2; }
      }

      // ---- P (C-layout) -> per-wave LDS (swizzled) ----
#pragma unroll
      for (int nt = 0; nt < 4; nt++)
#pragma unroll
        for (int i = 0; i < 4; i++) {
          const int row = fq * 4 + i, cc = nt * 16 + fr;
          const int scc = (cc & 7) | ((((cc >> 3) ^ (row & 7))) << 3);
          Ps[wave][0][row * 64 + scc] = bf16(sv1[nt][i]);
          Ps[wave][1][row * 64 + scc] = bf16(sv2[nt][i]);
        }

      // ---- PV ----
#pragma unroll
      for (int nt = 0; nt < 4; nt++) {
        const int vrow = nt * 16 + fr;
#pragma unroll
        for (int kk = 0; kk < 2; kk++) {
          const int pch = ((kk * 4 + fq) ^ (fr & 7)) * 8;
          const int vch = ((kk * 4 + fq) ^ (vrow & 7)) * 8;
          const s16x8 vf = ld8(&Vts[vrow * 64 + vch]);
          acc1[nt] = MFMA(ld8(&Ps[wave][0][fr * 64 + pch]), vf, acc1[nt]);
          acc2[nt] = MFMA(ld8(&Ps[wave][1][fr * 64 + pch]), vf, acc2[nt]);
        }
      }

#pragma unroll
      for (int nt = 0; nt < 4; nt++) cmb[nt] = cnx[nt];
      __syncthreads();
    }

    // ---- finalize: out = acc1/l1 - lam * acc2/l2 ----
    float r1v[4], r2v[4];
#pragma unroll
    for (int i = 0; i < 4; i++) { r1v[i] = 1.f / l1[i]; r2v[i] = lam / l2[i]; }
#pragma unroll
    for (int nt = 0; nt < 4; nt++)
#pragma unroll
      for (int i = 0; i < 4; i++) {
        X[((size_t)bh * NB_S + qw + fq * 4 + i) * NB_D + nt * 16 + fr] =
            acc1[nt][i] * r1v[i] - acc2[nt][i] * r2v[i];
      }
  }
}

// ---------------- GroupNorm over (b,h): stats then apply ----------------
__global__ __launch_bounds__(256) void gn_part(const float* __restrict__ X, float* __restrict__ part) {
  const int blk = blockIdx.x;  // bh = blk>>3, seg = blk&7
  const int bh = blk >> 3, seg = blk & 7;
  const float* xp = X + (size_t)bh * 131072 + (size_t)seg * 16384;
  float s = 0.f, s2 = 0.f;
  for (int i = threadIdx.x; i < 4096; i += 256) {
    fvec4 v = ((const fvec4*)xp)[i];
    s += v.x + v.y + v.z + v.w;
    s2 += v.x * v.x + v.y * v.y + v.z * v.z + v.w * v.w;
  }
#pragma unroll
  for (int o = 32; o; o >>= 1) { s += __shfl_xor(s, o); s2 += __shfl_xor(s2, o); }
  __shared__ float rs[4], rq[4];
  const int wv = threadIdx.x >> 6, ln = threadIdx.x & 63;
  if (ln == 0) { rs[wv] = s; rq[wv] = s2; }
  __syncthreads();
  if (threadIdx.x == 0) {
    part[blk * 2] = rs[0] + rs[1] + rs[2] + rs[3];
    part[blk * 2 + 1] = rq[0] + rq[1] + rq[2] + rq[3];
  }
}

__global__ __launch_bounds__(256) void gn_apply(const float* __restrict__ X,
                                                const float* __restrict__ part,
                                                const float* __restrict__ gw,
                                                const float* __restrict__ gb,
                                                bf16* __restrict__ Xn) {
  const int blk = blockIdx.x, bh = blk >> 3, seg = blk & 7;
  const int b = bh >> 4, h = bh & 15;
  float s = 0.f, s2 = 0.f;
#pragma unroll
  for (int i = 0; i < 8; i++) { s += part[(bh * 8 + i) * 2]; s2 += part[(bh * 8 + i) * 2 + 1]; }
  const float mean = s * (1.f / 131072.f);
  const float var = s2 * (1.f / 131072.f) - mean * mean;
  const float rstd = rsqrtf(var + 1e-5f) * 0.2f;  // fold (1-LAMBDA_INIT)
  const float* xp = X + (size_t)bh * 131072 + (size_t)seg * 16384;
  for (int i = threadIdx.x; i < 4096; i += 256) {
    fvec4 v = ((const fvec4*)xp)[i];
    const int e = seg * 16384 + i * 4;
    const int srow = e >> 6, d = e & 63;
    const int c = h * 64 + d;
    bf16x4 o = { bf16((v.x - mean) * rstd * gw[c]     + 0.2f * gb[c]),
                 bf16((v.y - mean) * rstd * gw[c + 1] + 0.2f * gb[c + 1]),
                 bf16((v.z - mean) * rstd * gw[c + 2] + 0.2f * gb[c + 2]),
                 bf16((v.w - mean) * rstd * gw[c + 3] + 0.2f * gb[c + 3]) };
    *(bf16x4*)(Xn + ((size_t)b * NB_S + srow) * 1024 + c) = o;
  }
}

// ---------------- launch ----------------
extern "C" void kernel_launch(void* const* d_in, const int* in_sizes, int n_in,
                              void* d_out, int out_size, void* d_ws, size_t ws_size,
                              hipStream_t stream) {
  const float* inputs = (const float*)d_in[0];
  const float* amask  = (const float*)d_in[1];
  const int*   tok    = (const int*)d_in[2];
  const float* Wq = (const float*)d_in[3];
  const float* Wk = (const float*)d_in[4];
  const float* Wv = (const float*)d_in[5];
  const float* Wo = (const float*)d_in[6];
  const float* lq1 = (const float*)d_in[7];
  const float* lq2 = (const float*)d_in[8];
  const float* lk1 = (const float*)d_in[9];
  const float* lk2 = (const float*)d_in[10];
  const float* gw = (const float*)d_in[11];
  const float* gb = (const float*)d_in[12];
  float* out = (float*)d_out;
  char* ws = (char*)d_ws;

  // workspace layout (sequential stream => WAR-safe aliasing):
  bf16* Xbf = (bf16*)(ws + 0);
  bf16* Wqb = (bf16*)(ws + 8388608);
  bf16* Wkb = (bf16*)(ws + 12582912);
  bf16* Wvb = (bf16*)(ws + 16777216);     // dead after V-proj gemm
  float* X  = (float*)(ws + 0);           // aliases Xbf/Wqb/Wkb (dead by attn)
  float* combo = (float*)(ws + 16777216); // aliases Wvb (written after V-proj)
  bf16* Qb  = (bf16*)(ws + 18874368);
  bf16* Xn  = (bf16*)(ws + 18874368);     // aliases Qb (dead after attn)
  bf16* Kb  = (bf16*)(ws + 35651584);
  bf16* Vtb = (bf16*)(ws + 52428800);
  bf16* Wob = (bf16*)(ws + 60817408);
  float* lam = (float*)(ws + 62914560);
  float* gnp = (float*)(ws + 62914816);

  const float QSCALE = 0.125f * 1.44269504088896340736f;  // 1/sqrt(D) * log2(e)

  cvt_kernel<<<4096, 256, 0, stream>>>(inputs, Xbf, 1048576);
  cvt_kernel<<<2048, 256, 0, stream>>>(Wq, Wqb, 524288);
  cvt_kernel<<<2048, 256, 0, stream>>>(Wk, Wkb, 524288);
  cvt_kernel<<<1024, 256, 0, stream>>>(Wv, Wvb, 262144);
  cvt_kernel<<<1024, 256, 0, stream>>>(Wo, Wob, 262144);
  lam_kernel<<<1, 64, 0, stream>>>(lq1, lq2, lk1, lk2, lam);

  gemm_bt<0><<<dim3(32, 16), 256, 0, stream>>>(Xbf, Wqb, Qb, nullptr, 1024, QSCALE);
  gemm_bt<0><<<dim3(32, 16), 256, 0, stream>>>(Xbf, Wkb, Kb, nullptr, 1024, 1.0f);
  gemm_bt<1><<<dim3(32, 8), 256, 0, stream>>>(Xbf, Wvb, Vtb, nullptr, 1024, 1.0f);

  combo_kernel<<<256, 256, 0, stream>>>(tok, amask, combo);  // after V-proj (aliases Wvb)

  attn_kernel<<<dim3(16, 32), 256, 0, stream>>>(Qb, Kb, Vtb, tok, combo, lam, X);

  gn_part<<<256, 256, 0, stream>>>(X, gnp);
  gn_apply<<<256, 256, 0, stream>>>(X, gnp, gw, gb, Xn);

  gemm_bt<2><<<dim3(32, 8), 256, 0, stream>>>(Xn, Wob, nullptr, out, 1024, 1.0f);
}

// Round 3
// 299.135 us; speedup vs baseline: 1.3484x; 1.1419x over previous
//
#include <hip/hip_runtime.h>
#include <hip/hip_bf16.h>

typedef __hip_bfloat16 bf16;
typedef float f32x4 __attribute__((ext_vector_type(4)));
typedef float fvec4 __attribute__((ext_vector_type(4)));
typedef short s16x8 __attribute__((ext_vector_type(8)));

#define NB_B 2
#define NB_S 2048
#define NB_E 1024
#define NB_H 16
#define NB_D 64

typedef const __attribute__((address_space(1))) void* GPTR;
typedef __attribute__((address_space(3))) void* LPTR;

__device__ __forceinline__ void gld16(const void* g, void* l) {
  __builtin_amdgcn_global_load_lds((GPTR)g, (LPTR)l, 16, 0, 0);
}

__device__ __forceinline__ s16x8 ld8(const bf16* p) { return *(const s16x8*)p; }

__device__ __forceinline__ f32x4 MFMA(s16x8 a, s16x8 b, f32x4 c) {
  return __builtin_amdgcn_mfma_f32_16x16x32_bf16(a, b, c, 0, 0, 0);
}

// ---------------- f32 -> bf16 convert ----------------
struct __align__(8) bf16x4 { bf16 a, b, c, d; };

__global__ void cvt_kernel(const float* __restrict__ in, bf16* __restrict__ out, int n4) {
  int i = blockIdx.x * blockDim.x + threadIdx.x;
  if (i >= n4) return;
  fvec4 v = ((const fvec4*)in)[i];
  bf16x4 o = { bf16(v.x), bf16(v.y), bf16(v.z), bf16(v.w) };
  ((bf16x4*)out)[i] = o;
}

// ---------------- lambda scalar ----------------
__global__ void lam_kernel(const float* lq1, const float* lq2,
                           const float* lk1, const float* lk2, float* out) {
  int l = threadIdx.x;  // 64 threads
  float d1 = lq1[l] * lk1[l];
  float d2 = lq2[l] * lk2[l];
#pragma unroll
  for (int o = 32; o; o >>= 1) { d1 += __shfl_xor(d1, o); d2 += __shfl_xor(d2, o); }
  if (l == 0) out[0] = expf(d1) - expf(d2) + 0.8f;
}

// ---------------- combo bias precompute: combo[h][b][s] = slopeL*tok + padL ----
__global__ void combo_kernel(const int* __restrict__ tok, const float* __restrict__ amask,
                             float* __restrict__ combo) {
  int i = blockIdx.x * 256 + threadIdx.x;  // H*B*S = 65536
  int hh = i >> 12, bs = i & 4095;
  float slopeL = exp2f(-0.5f * (float)(hh + 1)) * 1.44269504088896340736f;
  combo[i] = slopeL * (float)tok[bs] + (amask[bs] - 1.f) * 1.44269504e9f;
}

// ---------------- GEMM: C = A @ B^T (2-phase double-buffered) ----------------
template <int EPI>
__global__ __launch_bounds__(256) void gemm_bt(const bf16* __restrict__ A,
                                               const bf16* __restrict__ Bw,
                                               bf16* __restrict__ Ob,
                                               float* __restrict__ Of,
                                               int Kd, float oscale) {
  __shared__ bf16 As[2][128 * 32];
  __shared__ bf16 Bs[2][128 * 32];
  const int tid = threadIdx.x;
  const int lane = tid & 63;
  const int fr = lane & 15, fq = lane >> 4;
  const int wave = tid >> 6;
  const int wr = (wave >> 1) * 64, wc = (wave & 1) * 64;
  const size_t m0 = (size_t)blockIdx.x * 128, n0 = (size_t)blockIdx.y * 128;

  f32x4 acc[4][4];
#pragma unroll
  for (int i = 0; i < 4; i++)
#pragma unroll
    for (int j = 0; j < 4; j++) acc[i][j] = f32x4{0.f, 0.f, 0.f, 0.f};

  const int ca = tid, cb = tid + 256;
  const bf16* ga0 = A + (m0 + (ca >> 2)) * Kd + (ca & 3) * 8;
  const bf16* ga1 = A + (m0 + (cb >> 2)) * Kd + (cb & 3) * 8;
  const bf16* gb0 = Bw + (n0 + (ca >> 2)) * Kd + (ca & 3) * 8;
  const bf16* gb1 = Bw + (n0 + (cb >> 2)) * Kd + (cb & 3) * 8;

  gld16(ga0, &As[0][ca * 8]);
  gld16(ga1, &As[0][cb * 8]);
  gld16(gb0, &Bs[0][ca * 8]);
  gld16(gb1, &Bs[0][cb * 8]);
  __syncthreads();

  const int NKT = Kd >> 5;
  for (int kti = 0; kti < NKT; ++kti) {
    const int cur = kti & 1;
    if (kti + 1 < NKT) {
      const int kt = (kti + 1) << 5;
      gld16(ga0 + kt, &As[cur ^ 1][ca * 8]);
      gld16(ga1 + kt, &As[cur ^ 1][cb * 8]);
      gld16(gb0 + kt, &Bs[cur ^ 1][ca * 8]);
      gld16(gb1 + kt, &Bs[cur ^ 1][cb * 8]);
    }
    s16x8 af[4], bfv[4];
#pragma unroll
    for (int mi = 0; mi < 4; mi++) af[mi] = ld8(&As[cur][(wr + mi * 16 + fr) * 32 + fq * 8]);
#pragma unroll
    for (int ni = 0; ni < 4; ni++) bfv[ni] = ld8(&Bs[cur][(wc + ni * 16 + fr) * 32 + fq * 8]);
#pragma unroll
    for (int mi = 0; mi < 4; mi++)
#pragma unroll
      for (int ni = 0; ni < 4; ni++)
        acc[mi][ni] = MFMA(af[mi], bfv[ni], acc[mi][ni]);
    __syncthreads();
  }

#pragma unroll
  for (int mi = 0; mi < 4; mi++)
#pragma unroll
    for (int ni = 0; ni < 4; ni++)
#pragma unroll
      for (int i = 0; i < 4; i++) {
        size_t m = m0 + wr + mi * 16 + fq * 4 + i;
        size_t n = n0 + wc + ni * 16 + fr;
        float v = acc[mi][ni][i] * oscale;
        if constexpr (EPI == 0) {
          size_t b = m >> 11, s = m & 2047, h = n >> 7, dd = n & 127;
          Ob[((b * NB_H + h) * NB_S + s) * 128 + dd] = bf16(v);
        } else if constexpr (EPI == 1) {
          size_t b = m >> 11, s = m & 2047, h = n >> 6, d = n & 63;
          Ob[((b * NB_H + h) * NB_D + d) * NB_S + s] = bf16(v);
        } else {
          Of[m * 1024 + n] = v;
        }
      }
}

// ---------------- fused causal differential flash attention (swapped QK^T) ----
// Q/K: [b][h][s][128] bf16 (Q pre-scaled by 0.125*log2e). Vt: [b][h][d][s] bf16.
// combo: [h][b][s] f32. X out: [b][h][s][64] f32.
// Grid (16, 32): block handles q-blocks {x, 31-x} -> uniform 33 KV tiles.
// Swapped scores S[k][q] = mfma(K, Q): lane owns q = qw+fr, k = nt*16+fq*4+i.
__global__ __launch_bounds__(256, 3) void attn_kernel(
    const bf16* __restrict__ Q, const bf16* __restrict__ Kk, const bf16* __restrict__ Vt,
    const int* __restrict__ tok, const float* __restrict__ combo,
    const float* __restrict__ lamp, float* __restrict__ X) {
  __shared__ bf16 Ks[2][2][4096];  // [buf][set][64 k][64 d] swizzled  (32 KB)
  __shared__ bf16 Vs[4096];        // [64 d][64 s] swizzled, single buf (8 KB)
  __shared__ bf16 Ps[4][1024];     // per-wave P [16 q][64 k] swizzled (8 KB)

  const int tid = threadIdx.x, lane = tid & 63, wave = tid >> 6;
  const int fr = lane & 15, fq = lane >> 4;
  const int bh = blockIdx.y, b = bh >> 4, h = bh & 15;

  const float lam = lamp[0];
  const float slopeL = exp2f(-0.5f * (float)(h + 1)) * 1.44269504088896340736f;
  const float* comboH = combo + ((size_t)h * NB_B + b) * NB_S;

  const bf16* Kbase = Kk + (size_t)bh * NB_S * 128;
  const bf16* Vbase = Vt + (size_t)bh * NB_D * NB_S;

  // K staging: 1024 chunks/tile (set0 512 | set1 512), 4 per thread.
  const bf16* gK[4]; int lK[4];
#pragma unroll
  for (int i = 0; i < 4; i++) {
    int c = tid + i * 256, set = c >> 9, cc = c & 511;
    int row = cc >> 3, col8 = cc & 7, sc = col8 ^ (row & 7);
    gK[i] = Kbase + (size_t)row * 128 + set * 64 + sc * 8;
    lK[i] = set * 4096 + cc * 8;
  }
  // V staging: 512 chunks/tile, 2 per thread.
  const bf16* gV[2]; int lV[2];
#pragma unroll
  for (int i = 0; i < 2; i++) {
    int c = tid + i * 256;
    int row = c >> 3, col8 = c & 7, sc = col8 ^ (row & 7);
    gV[i] = Vbase + (size_t)row * NB_S + sc * 8;
    lV[i] = c * 8;
  }

  for (int qpass = 0; qpass < 2; ++qpass) {
    const int qb = qpass ? (31 - (int)blockIdx.x) : (int)blockIdx.x;
    const int q0 = qb * 64;
    const int qw = q0 + wave * 16;
    const int ntiles = qb + 1;

    // Q fragments: B-operand, lane = col q = qw+fr, d-slice = kk*32 + fq*8
    const bf16* qrow = Q + ((size_t)bh * NB_S + qw + fr) * 128;
    s16x8 q1[2], q2[2];
    q1[0] = ld8(qrow + fq * 8);       q1[1] = ld8(qrow + 32 + fq * 8);
    q2[0] = ld8(qrow + 64 + fq * 8);  q2[1] = ld8(qrow + 96 + fq * 8);

    const int qg = qw + fr;
    const float pq = slopeL * (float)tok[b * NB_S + qg];

    float m1 = -1e30f, m2 = -1e30f, l1 = 0.f, l2 = 0.f;
    f32x4 acc1[4], acc2[4];
#pragma unroll
    for (int nt = 0; nt < 4; nt++) { acc1[nt] = f32x4{0.f,0.f,0.f,0.f}; acc2[nt] = f32x4{0.f,0.f,0.f,0.f}; }

    // prologue: stage K[0] into buf0 + V[0]
#pragma unroll
    for (int i = 0; i < 4; i++) gld16(gK[i], &Ks[0][0][0] + lK[i]);
#pragma unroll
    for (int i = 0; i < 2; i++) gld16(gV[i], &Vs[0] + lV[i]);
    __syncthreads();

    for (int t = 0; t < ntiles; ++t) {
      const int cur = t & 1;
      const int kv0 = t * 64;
      // prefetch next K tile into other buffer (in flight across this tile)
      if (t + 1 < ntiles) {
#pragma unroll
        for (int i = 0; i < 4; i++)
          gld16(gK[i] + (size_t)(kv0 + 64) * 128, &Ks[cur ^ 1][0][0] + lK[i]);
      }
      // combo for this tile's k values (broadcast loads, hidden under QK)
      fvec4 cmbv[4];
#pragma unroll
      for (int nt = 0; nt < 4; nt++)
        cmbv[nt] = *(const fvec4*)(comboH + kv0 + nt * 16 + fq * 4);

      // ---- QK^T swapped: S[k][q], both sets ----
      f32x4 c1[4], c2[4];
#pragma unroll
      for (int nt = 0; nt < 4; nt++) { c1[nt] = f32x4{0.f,0.f,0.f,0.f}; c2[nt] = f32x4{0.f,0.f,0.f,0.f}; }
#pragma unroll
      for (int nt = 0; nt < 4; nt++) {
        const int krow = nt * 16 + fr;
#pragma unroll
        for (int kk = 0; kk < 2; kk++) {
          const int sch = ((kk * 4 + fq) ^ (krow & 7)) * 8;
          c1[nt] = MFMA(ld8(&Ks[cur][0][krow * 64 + sch]), q1[kk], c1[nt]);
          c2[nt] = MFMA(ld8(&Ks[cur][1][krow * 64 + sch]), q2[kk], c2[nt]);
        }
      }

      // ---- scores + bias (lane-local; k = kv0 + nt*16 + fq*4 + i, q = qg) ----
      float sv1[4][4], sv2[4][4];
#pragma unroll
      for (int nt = 0; nt < 4; nt++)
#pragma unroll
        for (int i = 0; i < 4; i++) {
          const float biasv = cmbv[nt][i] - pq;
          sv1[nt][i] = c1[nt][i] + biasv;
          sv2[nt][i] = c2[nt][i] + biasv;
        }
      if (t == ntiles - 1) {  // diagonal tile: causal mask
#pragma unroll
        for (int nt = 0; nt < 4; nt++)
#pragma unroll
          for (int i = 0; i < 4; i++)
            if (kv0 + nt * 16 + fq * 4 + i > qg) { sv1[nt][i] = -1e30f; sv2[nt][i] = -1e30f; }
      }

      // V fragments (shared by both sets; Vs holds V[t])
      s16x8 vf[4][2];
#pragma unroll
      for (int nt = 0; nt < 4; nt++) {
        const int vrow = nt * 16 + fr;
#pragma unroll
        for (int kk = 0; kk < 2; kk++)
          vf[nt][kk] = ld8(&Vs[vrow * 64 + (((kk * 4 + fq) ^ (vrow & 7)) << 3)]);
      }

      // ================= SET 1: softmax + P + PV =================
      {
        float pm = fmaxf(fmaxf(fmaxf(sv1[0][0], sv1[0][1]), fmaxf(sv1[0][2], sv1[0][3])),
                         fmaxf(fmaxf(sv1[1][0], sv1[1][1]), fmaxf(sv1[1][2], sv1[1][3])));
        pm = fmaxf(pm, fmaxf(fmaxf(fmaxf(sv1[2][0], sv1[2][1]), fmaxf(sv1[2][2], sv1[2][3])),
                             fmaxf(fmaxf(sv1[3][0], sv1[3][1]), fmaxf(sv1[3][2], sv1[3][3]))));
        pm = fmaxf(pm, __shfl_xor(pm, 16));
        pm = fmaxf(pm, __shfl_xor(pm, 32));
        if (__any(pm > m1 + 8.f)) {  // defer-max (T13)
          const float nm = fmaxf(m1, pm);
          const float cor = exp2f(m1 - nm);
          m1 = nm; l1 *= cor;
#pragma unroll
          for (int i = 0; i < 4; i++) {
            const float ci = __shfl(cor, fq * 4 + i);
#pragma unroll
            for (int nt = 0; nt < 4; nt++) acc1[nt][i] *= ci;
          }
        }
        float rs = 0.f;
#pragma unroll
        for (int nt = 0; nt < 4; nt++) {
          const float p0 = exp2f(sv1[nt][0] - m1), p1 = exp2f(sv1[nt][1] - m1);
          const float p2 = exp2f(sv1[nt][2] - m1), p3 = exp2f(sv1[nt][3] - m1);
          rs += (p0 + p1) + (p2 + p3);
          bf16x4 pk = { bf16(p0), bf16(p1), bf16(p2), bf16(p3) };
          *(bf16x4*)&Ps[wave][fr * 64 + ((((nt * 4 + fq) ^ ((fr & 7) << 1))) << 2)] = pk;
        }
        rs += __shfl_xor(rs, 16);
        rs += __shfl_xor(rs, 32);
        l1 += rs;
#pragma unroll
        for (int kk = 0; kk < 2; kk++) {
          const s16x8 pa = ld8(&Ps[wave][fr * 64 + (((kk * 8 + fq * 2) ^ ((fr & 7) << 1)) << 2)]);
#pragma unroll
          for (int nt = 0; nt < 4; nt++) acc1[nt] = MFMA(pa, vf[nt][kk], acc1[nt]);
        }
      }
      // ================= SET 2: softmax + P + PV =================
      {
        float pm = fmaxf(fmaxf(fmaxf(sv2[0][0], sv2[0][1]), fmaxf(sv2[0][2], sv2[0][3])),
                         fmaxf(fmaxf(sv2[1][0], sv2[1][1]), fmaxf(sv2[1][2], sv2[1][3])));
        pm = fmaxf(pm, fmaxf(fmaxf(fmaxf(sv2[2][0], sv2[2][1]), fmaxf(sv2[2][2], sv2[2][3])),
                             fmaxf(fmaxf(sv2[3][0], sv2[3][1]), fmaxf(sv2[3][2], sv2[3][3]))));
        pm = fmaxf(pm, __shfl_xor(pm, 16));
        pm = fmaxf(pm, __shfl_xor(pm, 32));
        if (__any(pm > m2 + 8.f)) {
          const float nm = fmaxf(m2, pm);
          const float cor = exp2f(m2 - nm);
          m2 = nm; l2 *= cor;
#pragma unroll
          for (int i = 0; i < 4; i++) {
            const float ci = __shfl(cor, fq * 4 + i);
#pragma unroll
            for (int nt = 0; nt < 4; nt++) acc2[nt][i] *= ci;
          }
        }
        float rs = 0.f;
#pragma unroll
        for (int nt = 0; nt < 4; nt++) {
          const float p0 = exp2f(sv2[nt][0] - m2), p1 = exp2f(sv2[nt][1] - m2);
          const float p2 = exp2f(sv2[nt][2] - m2), p3 = exp2f(sv2[nt][3] - m2);
          rs += (p0 + p1) + (p2 + p3);
          bf16x4 pk = { bf16(p0), bf16(p1), bf16(p2), bf16(p3) };
          *(bf16x4*)&Ps[wave][fr * 64 + ((((nt * 4 + fq) ^ ((fr & 7) << 1))) << 2)] = pk;
        }
        rs += __shfl_xor(rs, 16);
        rs += __shfl_xor(rs, 32);
        l2 += rs;
#pragma unroll
        for (int kk = 0; kk < 2; kk++) {
          const s16x8 pa = ld8(&Ps[wave][fr * 64 + (((kk * 8 + fq * 2) ^ ((fr & 7) << 1)) << 2)]);
#pragma unroll
          for (int nt = 0; nt < 4; nt++) acc2[nt] = MFMA(pa, vf[nt][kk], acc2[nt]);
        }
      }

      __syncthreads();  // all waves done reading Vs (and Ks[cur])
      if (t + 1 < ntiles) {
#pragma unroll
        for (int i = 0; i < 2; i++) gld16(gV[i] + (size_t)(kv0 + 64), &Vs[0] + lV[i]);
      }
      __syncthreads();  // drains vmcnt -> K[t+1] and V[t+1] ready
    }

    // ---- finalize: out = acc1/l1 - lam * acc2/l2 ----
    const float r1 = 1.f / l1, r2 = lam / l2;
    float r1b[4], r2b[4];
#pragma unroll
    for (int i = 0; i < 4; i++) {
      r1b[i] = __shfl(r1, fq * 4 + i);
      r2b[i] = __shfl(r2, fq * 4 + i);
    }
#pragma unroll
    for (int nt = 0; nt < 4; nt++)
#pragma unroll
      for (int i = 0; i < 4; i++) {
        X[((size_t)bh * NB_S + qw + fq * 4 + i) * NB_D + nt * 16 + fr] =
            acc1[nt][i] * r1b[i] - acc2[nt][i] * r2b[i];
      }
  }
}

// ---------------- GroupNorm over (b,h): stats then apply ----------------
__global__ __launch_bounds__(256) void gn_part(const float* __restrict__ X, float* __restrict__ part) {
  const int blk = blockIdx.x;
  const int bh = blk >> 3, seg = blk & 7;
  const float* xp = X + (size_t)bh * 131072 + (size_t)seg * 16384;
  float s = 0.f, s2 = 0.f;
  for (int i = threadIdx.x; i < 4096; i += 256) {
    fvec4 v = ((const fvec4*)xp)[i];
    s += v.x + v.y + v.z + v.w;
    s2 += v.x * v.x + v.y * v.y + v.z * v.z + v.w * v.w;
  }
#pragma unroll
  for (int o = 32; o; o >>= 1) { s += __shfl_xor(s, o); s2 += __shfl_xor(s2, o); }
  __shared__ float rs[4], rq[4];
  const int wv = threadIdx.x >> 6, ln = threadIdx.x & 63;
  if (ln == 0) { rs[wv] = s; rq[wv] = s2; }
  __syncthreads();
  if (threadIdx.x == 0) {
    part[blk * 2] = rs[0] + rs[1] + rs[2] + rs[3];
    part[blk * 2 + 1] = rq[0] + rq[1] + rq[2] + rq[3];
  }
}

__global__ __launch_bounds__(256) void gn_apply(const float* __restrict__ X,
                                                const float* __restrict__ part,
                                                const float* __restrict__ gw,
                                                const float* __restrict__ gb,
                                                bf16* __restrict__ Xn) {
  const int blk = blockIdx.x, bh = blk >> 3, seg = blk & 7;
  const int b = bh >> 4, h = bh & 15;
  float s = 0.f, s2 = 0.f;
#pragma unroll
  for (int i = 0; i < 8; i++) { s += part[(bh * 8 + i) * 2]; s2 += part[(bh * 8 + i) * 2 + 1]; }
  const float mean = s * (1.f / 131072.f);
  const float var = s2 * (1.f / 131072.f) - mean * mean;
  const float rstd = rsqrtf(var + 1e-5f) * 0.2f;
  const float* xp = X + (size_t)bh * 131072 + (size_t)seg * 16384;
  for (int i = threadIdx.x; i < 4096; i += 256) {
    fvec4 v = ((const fvec4*)xp)[i];
    const int e = seg * 16384 + i * 4;
    const int srow = e >> 6, d = e & 63;
    const int c = h * 64 + d;
    bf16x4 o = { bf16((v.x - mean) * rstd * gw[c]     + 0.2f * gb[c]),
                 bf16((v.y - mean) * rstd * gw[c + 1] + 0.2f * gb[c + 1]),
                 bf16((v.z - mean) * rstd * gw[c + 2] + 0.2f * gb[c + 2]),
                 bf16((v.w - mean) * rstd * gw[c + 3] + 0.2f * gb[c + 3]) };
    *(bf16x4*)(Xn + ((size_t)b * NB_S + srow) * 1024 + c) = o;
  }
}

// ---------------- launch ----------------
extern "C" void kernel_launch(void* const* d_in, const int* in_sizes, int n_in,
                              void* d_out, int out_size, void* d_ws, size_t ws_size,
                              hipStream_t stream) {
  const float* inputs = (const float*)d_in[0];
  const float* amask  = (const float*)d_in[1];
  const int*   tok    = (const int*)d_in[2];
  const float* Wq = (const float*)d_in[3];
  const float* Wk = (const float*)d_in[4];
  const float* Wv = (const float*)d_in[5];
  const float* Wo = (const float*)d_in[6];
  const float* lq1 = (const float*)d_in[7];
  const float* lq2 = (const float*)d_in[8];
  const float* lk1 = (const float*)d_in[9];
  const float* lk2 = (const float*)d_in[10];
  const float* gw = (const float*)d_in[11];
  const float* gb = (const float*)d_in[12];
  float* out = (float*)d_out;
  char* ws = (char*)d_ws;

  bf16* Xbf = (bf16*)(ws + 0);
  bf16* Wqb = (bf16*)(ws + 8388608);
  bf16* Wkb = (bf16*)(ws + 12582912);
  bf16* Wvb = (bf16*)(ws + 16777216);     // dead after V-proj gemm
  float* X  = (float*)(ws + 0);           // aliases Xbf/Wqb/Wkb (dead by attn)
  float* combo = (float*)(ws + 16777216); // aliases Wvb (written after V-proj)
  bf16* Qb  = (bf16*)(ws + 18874368);
  bf16* Xn  = (bf16*)(ws + 18874368);     // aliases Qb (dead after attn)
  bf16* Kb  = (bf16*)(ws + 35651584);
  bf16* Vtb = (bf16*)(ws + 52428800);
  bf16* Wob = (bf16*)(ws + 60817408);
  float* lam = (float*)(ws + 62914560);
  float* gnp = (float*)(ws + 62914816);

  const float QSCALE = 0.125f * 1.44269504088896340736f;  // 1/sqrt(D) * log2(e)

  cvt_kernel<<<4096, 256, 0, stream>>>(inputs, Xbf, 1048576);
  cvt_kernel<<<2048, 256, 0, stream>>>(Wq, Wqb, 524288);
  cvt_kernel<<<2048, 256, 0, stream>>>(Wk, Wkb, 524288);
  cvt_kernel<<<1024, 256, 0, stream>>>(Wv, Wvb, 262144);
  cvt_kernel<<<1024, 256, 0, stream>>>(Wo, Wob, 262144);
  lam_kernel<<<1, 64, 0, stream>>>(lq1, lq2, lk1, lk2, lam);

  gemm_bt<0><<<dim3(32, 16), 256, 0, stream>>>(Xbf, Wqb, Qb, nullptr, 1024, QSCALE);
  gemm_bt<0><<<dim3(32, 16), 256, 0, stream>>>(Xbf, Wkb, Kb, nullptr, 1024, 1.0f);
  gemm_bt<1><<<dim3(32, 8), 256, 0, stream>>>(Xbf, Wvb, Vtb, nullptr, 1024, 1.0f);

  combo_kernel<<<256, 256, 0, stream>>>(tok, amask, combo);

  attn_kernel<<<dim3(16, 32), 256, 0, stream>>>(Qb, Kb, Vtb, tok, combo, lam, X);

  gn_part<<<256, 256, 0, stream>>>(X, gnp);
  gn_apply<<<256, 256, 0, stream>>>(X, gnp, gw, gb, Xn);

  gemm_bt<2><<<dim3(32, 8), 256, 0, stream>>>(Xn, Wob, nullptr, out, 1024, 1.0f);
}

// Round 4
// 267.896 us; speedup vs baseline: 1.5057x; 1.1166x over previous
//
#include <hip/hip_runtime.h>
#include <hip/hip_bf16.h>

typedef __hip_bfloat16 bf16;
typedef float f32x4 __attribute__((ext_vector_type(4)));
typedef float fvec4 __attribute__((ext_vector_type(4)));
typedef short s16x8 __attribute__((ext_vector_type(8)));

#define NB_B 2
#define NB_S 2048
#define NB_E 1024
#define NB_H 16
#define NB_D 64

typedef const __attribute__((address_space(1))) void* GPTR;
typedef __attribute__((address_space(3))) void* LPTR;

__device__ __forceinline__ void gld16(const void* g, void* l) {
  __builtin_amdgcn_global_load_lds((GPTR)g, (LPTR)l, 16, 0, 0);
}

__device__ __forceinline__ s16x8 ld8(const bf16* p) { return *(const s16x8*)p; }

__device__ __forceinline__ f32x4 MFMA(s16x8 a, s16x8 b, f32x4 c) {
  return __builtin_amdgcn_mfma_f32_16x16x32_bf16(a, b, c, 0, 0, 0);
}

// ---------------- f32 -> bf16 convert ----------------
struct __align__(8) bf16x4 { bf16 a, b, c, d; };

__global__ void cvt_kernel(const float* __restrict__ in, bf16* __restrict__ out, int n4) {
  int i = blockIdx.x * blockDim.x + threadIdx.x;
  if (i >= n4) return;
  fvec4 v = ((const fvec4*)in)[i];
  bf16x4 o = { bf16(v.x), bf16(v.y), bf16(v.z), bf16(v.w) };
  ((bf16x4*)out)[i] = o;
}

// ---------------- lambda scalar ----------------
__global__ void lam_kernel(const float* lq1, const float* lq2,
                           const float* lk1, const float* lk2, float* out) {
  int l = threadIdx.x;  // 64 threads
  float d1 = lq1[l] * lk1[l];
  float d2 = lq2[l] * lk2[l];
#pragma unroll
  for (int o = 32; o; o >>= 1) { d1 += __shfl_xor(d1, o); d2 += __shfl_xor(d2, o); }
  if (l == 0) out[0] = expf(d1) - expf(d2) + 0.8f;
}

// ---------------- combo bias precompute: combo[h][b][s] = slopeL*tok + padL ----
__global__ void combo_kernel(const int* __restrict__ tok, const float* __restrict__ amask,
                             float* __restrict__ combo) {
  int i = blockIdx.x * 256 + threadIdx.x;  // H*B*S = 65536
  int hh = i >> 12, bs = i & 4095;
  float slopeL = exp2f(-0.5f * (float)(hh + 1)) * 1.44269504088896340736f;
  combo[i] = slopeL * (float)tok[bs] + (amask[bs] - 1.f) * 1.44269504e9f;
}

// ---------------- GEMM: C = A @ B^T (2-phase double-buffered) ----------------
// EPI 0: bf16 out; n<2048 -> Ob (Q, scaled by oscale), n>=2048 -> Ob2 (K, x1)
// EPI 1: bf16 out to [b][h][d][s]     (V proj transposed)
// EPI 2: f32 out row-major ld=1024    (final out proj)
template <int EPI>
__global__ __launch_bounds__(256) void gemm_bt(const bf16* __restrict__ A,
                                               const bf16* __restrict__ Bw,
                                               bf16* __restrict__ Ob,
                                               bf16* __restrict__ Ob2,
                                               float* __restrict__ Of,
                                               int Kd, float oscale) {
  __shared__ bf16 As[2][128 * 32];
  __shared__ bf16 Bs[2][128 * 32];
  const int tid = threadIdx.x;
  const int lane = tid & 63;
  const int fr = lane & 15, fq = lane >> 4;
  const int wave = tid >> 6;
  const int wr = (wave >> 1) * 64, wc = (wave & 1) * 64;
  const size_t m0 = (size_t)blockIdx.x * 128, n0 = (size_t)blockIdx.y * 128;

  f32x4 acc[4][4];
#pragma unroll
  for (int i = 0; i < 4; i++)
#pragma unroll
    for (int j = 0; j < 4; j++) acc[i][j] = f32x4{0.f, 0.f, 0.f, 0.f};

  const int ca = tid, cb = tid + 256;
  const bf16* ga0 = A + (m0 + (ca >> 2)) * Kd + (ca & 3) * 8;
  const bf16* ga1 = A + (m0 + (cb >> 2)) * Kd + (cb & 3) * 8;
  const bf16* gb0 = Bw + (n0 + (ca >> 2)) * Kd + (ca & 3) * 8;
  const bf16* gb1 = Bw + (n0 + (cb >> 2)) * Kd + (cb & 3) * 8;

  gld16(ga0, &As[0][ca * 8]);
  gld16(ga1, &As[0][cb * 8]);
  gld16(gb0, &Bs[0][ca * 8]);
  gld16(gb1, &Bs[0][cb * 8]);
  __syncthreads();

  const int NKT = Kd >> 5;
  for (int kti = 0; kti < NKT; ++kti) {
    const int cur = kti & 1;
    if (kti + 1 < NKT) {
      const int kt = (kti + 1) << 5;
      gld16(ga0 + kt, &As[cur ^ 1][ca * 8]);
      gld16(ga1 + kt, &As[cur ^ 1][cb * 8]);
      gld16(gb0 + kt, &Bs[cur ^ 1][ca * 8]);
      gld16(gb1 + kt, &Bs[cur ^ 1][cb * 8]);
    }
    s16x8 af[4], bfv[4];
#pragma unroll
    for (int mi = 0; mi < 4; mi++) af[mi] = ld8(&As[cur][(wr + mi * 16 + fr) * 32 + fq * 8]);
#pragma unroll
    for (int ni = 0; ni < 4; ni++) bfv[ni] = ld8(&Bs[cur][(wc + ni * 16 + fr) * 32 + fq * 8]);
#pragma unroll
    for (int mi = 0; mi < 4; mi++)
#pragma unroll
      for (int ni = 0; ni < 4; ni++)
        acc[mi][ni] = MFMA(af[mi], bfv[ni], acc[mi][ni]);
    __syncthreads();
  }

  // block-uniform Q/K select for fused QK projection
  bf16* dstQK = Ob;
  size_t nsub = 0;
  float osc = oscale;
  if constexpr (EPI == 0) {
    if (n0 >= 2048) { dstQK = Ob2; nsub = 2048; osc = 1.0f; }
  }

#pragma unroll
  for (int mi = 0; mi < 4; mi++)
#pragma unroll
    for (int ni = 0; ni < 4; ni++)
#pragma unroll
      for (int i = 0; i < 4; i++) {
        size_t m = m0 + wr + mi * 16 + fq * 4 + i;
        size_t n = n0 + wc + ni * 16 + fr;
        if constexpr (EPI == 0) {
          float v = acc[mi][ni][i] * osc;
          size_t nn = n - nsub;
          size_t b = m >> 11, s = m & 2047, h = nn >> 7, dd = nn & 127;
          dstQK[((b * NB_H + h) * NB_S + s) * 128 + dd] = bf16(v);
        } else if constexpr (EPI == 1) {
          float v = acc[mi][ni][i] * oscale;
          size_t b = m >> 11, s = m & 2047, h = n >> 6, d = n & 63;
          Ob[((b * NB_H + h) * NB_D + d) * NB_S + s] = bf16(v);
        } else {
          Of[m * 1024 + n] = acc[mi][ni][i] * oscale;
        }
      }
}

// ---------------- fused causal differential flash attention (swapped QK^T) ----
// Q/K: [b][h][s][128] bf16 (Q pre-scaled by 0.125*log2e). Vt: [b][h][d][s] bf16.
// combo: [h][b][s] f32. X out: [b][h][s][64] f32.
// Grid: 1024 1-D blocks. XCD swizzle: bh = (id&7)*4 + ((id>>3)&3) pins each bh's
// 32 q-blocks to one XCD (L2 reuse); qb = 31-(id>>5) dispatches big blocks first.
// Swapped scores S[k][q] = mfma(K, Q): lane owns q = qw+fr, k = nt*16+fq*4+i.
__global__ __launch_bounds__(256, 3) void attn_kernel(
    const bf16* __restrict__ Q, const bf16* __restrict__ Kk, const bf16* __restrict__ Vt,
    const int* __restrict__ tok, const float* __restrict__ combo,
    const float* __restrict__ lamp, float* __restrict__ X) {
  __shared__ bf16 Ks[2][2][4096];  // [buf][set][64 k][64 d] swizzled  (32 KB)
  __shared__ bf16 Vs[4096];        // [64 d][64 s] swizzled, single buf (8 KB)
  __shared__ bf16 Ps[4][1024];     // per-wave P [16 q][64 k] swizzled (8 KB)

  const int tid = threadIdx.x, lane = tid & 63, wave = tid >> 6;
  const int fr = lane & 15, fq = lane >> 4;
  const int id = blockIdx.x;
  const int bh = (id & 7) * 4 + ((id >> 3) & 3);
  const int qb = 31 - (id >> 5);
  const int b = bh >> 4, h = bh & 15;

  const float lam = lamp[0];
  const float slopeL = exp2f(-0.5f * (float)(h + 1)) * 1.44269504088896340736f;
  const float* comboH = combo + ((size_t)h * NB_B + b) * NB_S;

  const bf16* Kbase = Kk + (size_t)bh * NB_S * 128;
  const bf16* Vbase = Vt + (size_t)bh * NB_D * NB_S;

  // K staging: 1024 chunks/tile (set0 512 | set1 512), 4 per thread.
  const bf16* gK[4]; int lK[4];
#pragma unroll
  for (int i = 0; i < 4; i++) {
    int c = tid + i * 256, set = c >> 9, cc = c & 511;
    int row = cc >> 3, col8 = cc & 7, sc = col8 ^ (row & 7);
    gK[i] = Kbase + (size_t)row * 128 + set * 64 + sc * 8;
    lK[i] = set * 4096 + cc * 8;
  }
  // V: 512 chunks/tile, 2 per thread (reg-staged after prologue).
  const bf16* gV[2]; int lV[2];
#pragma unroll
  for (int i = 0; i < 2; i++) {
    int c = tid + i * 256;
    int row = c >> 3, col8 = c & 7, sc = col8 ^ (row & 7);
    gV[i] = Vbase + (size_t)row * NB_S + sc * 8;
    lV[i] = c * 8;
  }

  const int q0 = qb * 64;
  const int qw = q0 + wave * 16;
  const int ntiles = qb + 1;

  // Q fragments: B-operand, lane = col q = qw+fr, d-slice = kk*32 + fq*8
  const bf16* qrow = Q + ((size_t)bh * NB_S + qw + fr) * 128;
  s16x8 q1[2], q2[2];
  q1[0] = ld8(qrow + fq * 8);       q1[1] = ld8(qrow + 32 + fq * 8);
  q2[0] = ld8(qrow + 64 + fq * 8);  q2[1] = ld8(qrow + 96 + fq * 8);

  const int qg = qw + fr;
  const float pq = slopeL * (float)tok[b * NB_S + qg];

  float m1 = -1e30f, m2 = -1e30f, l1 = 0.f, l2 = 0.f;
  f32x4 acc1[4], acc2[4];
#pragma unroll
  for (int nt = 0; nt < 4; nt++) { acc1[nt] = f32x4{0.f,0.f,0.f,0.f}; acc2[nt] = f32x4{0.f,0.f,0.f,0.f}; }

  // prologue: stage K[0] + V[0] direct to LDS
#pragma unroll
  for (int i = 0; i < 4; i++) gld16(gK[i], &Ks[0][0][0] + lK[i]);
#pragma unroll
  for (int i = 0; i < 2; i++) gld16(gV[i], &Vs[0] + lV[i]);
  __syncthreads();

  for (int t = 0; t < ntiles; ++t) {
    const int cur = t & 1;
    const int kv0 = t * 64;
    // prefetch next tile: K -> LDS (other buf), V -> registers (T14)
    fvec4 vreg[2];
    if (t + 1 < ntiles) {
#pragma unroll
      for (int i = 0; i < 2; i++) vreg[i] = *(const fvec4*)(gV[i] + (size_t)(kv0 + 64));
#pragma unroll
      for (int i = 0; i < 4; i++)
        gld16(gK[i] + (size_t)(kv0 + 64) * 128, &Ks[cur ^ 1][0][0] + lK[i]);
    }
    // combo for this tile's k values (broadcast loads, hidden under QK)
    fvec4 cmbv[4];
#pragma unroll
    for (int nt = 0; nt < 4; nt++)
      cmbv[nt] = *(const fvec4*)(comboH + kv0 + nt * 16 + fq * 4);

    // ---- QK^T swapped: S[k][q], both sets ----
    f32x4 c1[4], c2[4];
#pragma unroll
    for (int nt = 0; nt < 4; nt++) { c1[nt] = f32x4{0.f,0.f,0.f,0.f}; c2[nt] = f32x4{0.f,0.f,0.f,0.f}; }
#pragma unroll
    for (int nt = 0; nt < 4; nt++) {
      const int krow = nt * 16 + fr;
#pragma unroll
      for (int kk = 0; kk < 2; kk++) {
        const int sch = ((kk * 4 + fq) ^ (krow & 7)) * 8;
        c1[nt] = MFMA(ld8(&Ks[cur][0][krow * 64 + sch]), q1[kk], c1[nt]);
        c2[nt] = MFMA(ld8(&Ks[cur][1][krow * 64 + sch]), q2[kk], c2[nt]);
      }
    }

    // ---- scores + bias (lane-local; k = kv0 + nt*16 + fq*4 + i, q = qg) ----
    float sv1[4][4], sv2[4][4];
#pragma unroll
    for (int nt = 0; nt < 4; nt++)
#pragma unroll
      for (int i = 0; i < 4; i++) {
        const float biasv = cmbv[nt][i] - pq;
        sv1[nt][i] = c1[nt][i] + biasv;
        sv2[nt][i] = c2[nt][i] + biasv;
      }
    if (t == ntiles - 1) {  // diagonal tile: causal mask
#pragma unroll
      for (int nt = 0; nt < 4; nt++)
#pragma unroll
        for (int i = 0; i < 4; i++)
          if (kv0 + nt * 16 + fq * 4 + i > qg) { sv1[nt][i] = -1e30f; sv2[nt][i] = -1e30f; }
    }

    // V fragments (shared by both sets; Vs holds V[t])
    s16x8 vf[4][2];
#pragma unroll
    for (int nt = 0; nt < 4; nt++) {
      const int vrow = nt * 16 + fr;
#pragma unroll
      for (int kk = 0; kk < 2; kk++)
        vf[nt][kk] = ld8(&Vs[vrow * 64 + (((kk * 4 + fq) ^ (vrow & 7)) << 3)]);
    }

    // ================= SET 1: softmax + P + PV =================
    {
      float pm = fmaxf(fmaxf(fmaxf(sv1[0][0], sv1[0][1]), fmaxf(sv1[0][2], sv1[0][3])),
                       fmaxf(fmaxf(sv1[1][0], sv1[1][1]), fmaxf(sv1[1][2], sv1[1][3])));
      pm = fmaxf(pm, fmaxf(fmaxf(fmaxf(sv1[2][0], sv1[2][1]), fmaxf(sv1[2][2], sv1[2][3])),
                           fmaxf(fmaxf(sv1[3][0], sv1[3][1]), fmaxf(sv1[3][2], sv1[3][3]))));
      pm = fmaxf(pm, __shfl_xor(pm, 16));
      pm = fmaxf(pm, __shfl_xor(pm, 32));
      if (__any(pm > m1 + 8.f)) {  // defer-max (T13)
        const float nm = fmaxf(m1, pm);
        const float cor = exp2f(m1 - nm);
        m1 = nm; l1 *= cor;
#pragma unroll
        for (int i = 0; i < 4; i++) {
          const float ci = __shfl(cor, fq * 4 + i);
#pragma unroll
          for (int nt = 0; nt < 4; nt++) acc1[nt][i] *= ci;
        }
      }
      float rs = 0.f;
#pragma unroll
      for (int nt = 0; nt < 4; nt++) {
        const float p0 = exp2f(sv1[nt][0] - m1), p1 = exp2f(sv1[nt][1] - m1);
        const float p2 = exp2f(sv1[nt][2] - m1), p3 = exp2f(sv1[nt][3] - m1);
        rs += (p0 + p1) + (p2 + p3);
        bf16x4 pk = { bf16(p0), bf16(p1), bf16(p2), bf16(p3) };
        *(bf16x4*)&Ps[wave][fr * 64 + ((((nt * 4 + fq) ^ ((fr & 7) << 1))) << 2)] = pk;
      }
      rs += __shfl_xor(rs, 16);
      rs += __shfl_xor(rs, 32);
      l1 += rs;
#pragma unroll
      for (int kk = 0; kk < 2; kk++) {
        const s16x8 pa = ld8(&Ps[wave][fr * 64 + (((kk * 8 + fq * 2) ^ ((fr & 7) << 1)) << 2)]);
#pragma unroll
        for (int nt = 0; nt < 4; nt++) acc1[nt] = MFMA(pa, vf[nt][kk], acc1[nt]);
      }
    }
    // ================= SET 2: softmax + P + PV =================
    {
      float pm = fmaxf(fmaxf(fmaxf(sv2[0][0], sv2[0][1]), fmaxf(sv2[0][2], sv2[0][3])),
                       fmaxf(fmaxf(sv2[1][0], sv2[1][1]), fmaxf(sv2[1][2], sv2[1][3])));
      pm = fmaxf(pm, fmaxf(fmaxf(fmaxf(sv2[2][0], sv2[2][1]), fmaxf(sv2[2][2], sv2[2][3])),
                           fmaxf(fmaxf(sv2[3][0], sv2[3][1]), fmaxf(sv2[3][2], sv2[3][3]))));
      pm = fmaxf(pm, __shfl_xor(pm, 16));
      pm = fmaxf(pm, __shfl_xor(pm, 32));
      if (__any(pm > m2 + 8.f)) {
        const float nm = fmaxf(m2, pm);
        const float cor = exp2f(m2 - nm);
        m2 = nm; l2 *= cor;
#pragma unroll
        for (int i = 0; i < 4; i++) {
          const float ci = __shfl(cor, fq * 4 + i);
#pragma unroll
          for (int nt = 0; nt < 4; nt++) acc2[nt][i] *= ci;
        }
      }
      float rs = 0.f;
#pragma unroll
      for (int nt = 0; nt < 4; nt++) {
        const float p0 = exp2f(sv2[nt][0] - m2), p1 = exp2f(sv2[nt][1] - m2);
        const float p2 = exp2f(sv2[nt][2] - m2), p3 = exp2f(sv2[nt][3] - m2);
        rs += (p0 + p1) + (p2 + p3);
        bf16x4 pk = { bf16(p0), bf16(p1), bf16(p2), bf16(p3) };
        *(bf16x4*)&Ps[wave][fr * 64 + ((((nt * 4 + fq) ^ ((fr & 7) << 1))) << 2)] = pk;
      }
      rs += __shfl_xor(rs, 16);
      rs += __shfl_xor(rs, 32);
      l2 += rs;
#pragma unroll
      for (int kk = 0; kk < 2; kk++) {
        const s16x8 pa = ld8(&Ps[wave][fr * 64 + (((kk * 8 + fq * 2) ^ ((fr & 7) << 1)) << 2)]);
#pragma unroll
        for (int nt = 0; nt < 4; nt++) acc2[nt] = MFMA(pa, vf[nt][kk], acc2[nt]);
      }
    }

    __syncthreads();  // all waves done reading Vs; drains K[t+1] + vreg loads
    if (t + 1 < ntiles) {
#pragma unroll
      for (int i = 0; i < 2; i++) *(fvec4*)(&Vs[lV[i]]) = vreg[i];  // ds_write V[t+1]
    }
    __syncthreads();  // V written (lgkm only -- cheap)
  }

  // ---- finalize: out = acc1/l1 - lam * acc2/l2 ----
  const float r1 = 1.f / l1, r2 = lam / l2;
  float r1b[4], r2b[4];
#pragma unroll
  for (int i = 0; i < 4; i++) {
    r1b[i] = __shfl(r1, fq * 4 + i);
    r2b[i] = __shfl(r2, fq * 4 + i);
  }
#pragma unroll
  for (int nt = 0; nt < 4; nt++)
#pragma unroll
    for (int i = 0; i < 4; i++) {
      X[((size_t)bh * NB_S + qw + fq * 4 + i) * NB_D + nt * 16 + fr] =
          acc1[nt][i] * r1b[i] - acc2[nt][i] * r2b[i];
    }
}

// ---------------- GroupNorm over (b,h): stats then apply ----------------
__global__ __launch_bounds__(256) void gn_part(const float* __restrict__ X, float* __restrict__ part) {
  const int blk = blockIdx.x;
  const int bh = blk >> 3, seg = blk & 7;
  const float* xp = X + (size_t)bh * 131072 + (size_t)seg * 16384;
  float s = 0.f, s2 = 0.f;
  for (int i = threadIdx.x; i < 4096; i += 256) {
    fvec4 v = ((const fvec4*)xp)[i];
    s += v.x + v.y + v.z + v.w;
    s2 += v.x * v.x + v.y * v.y + v.z * v.z + v.w * v.w;
  }
#pragma unroll
  for (int o = 32; o; o >>= 1) { s += __shfl_xor(s, o); s2 += __shfl_xor(s2, o); }
  __shared__ float rs[4], rq[4];
  const int wv = threadIdx.x >> 6, ln = threadIdx.x & 63;
  if (ln == 0) { rs[wv] = s; rq[wv] = s2; }
  __syncthreads();
  if (threadIdx.x == 0) {
    part[blk * 2] = rs[0] + rs[1] + rs[2] + rs[3];
    part[blk * 2 + 1] = rq[0] + rq[1] + rq[2] + rq[3];
  }
}

__global__ __launch_bounds__(256) void gn_apply(const float* __restrict__ X,
                                                const float* __restrict__ part,
                                                const float* __restrict__ gw,
                                                const float* __restrict__ gb,
                                                bf16* __restrict__ Xn) {
  const int blk = blockIdx.x, bh = blk >> 3, seg = blk & 7;
  const int b = bh >> 4, h = bh & 15;
  float s = 0.f, s2 = 0.f;
#pragma unroll
  for (int i = 0; i < 8; i++) { s += part[(bh * 8 + i) * 2]; s2 += part[(bh * 8 + i) * 2 + 1]; }
  const float mean = s * (1.f / 131072.f);
  const float var = s2 * (1.f / 131072.f) - mean * mean;
  const float rstd = rsqrtf(var + 1e-5f) * 0.2f;
  const float* xp = X + (size_t)bh * 131072 + (size_t)seg * 16384;
  for (int i = threadIdx.x; i < 4096; i += 256) {
    fvec4 v = ((const fvec4*)xp)[i];
    const int e = seg * 16384 + i * 4;
    const int srow = e >> 6, d = e & 63;
    const int c = h * 64 + d;
    bf16x4 o = { bf16((v.x - mean) * rstd * gw[c]     + 0.2f * gb[c]),
                 bf16((v.y - mean) * rstd * gw[c + 1] + 0.2f * gb[c + 1]),
                 bf16((v.z - mean) * rstd * gw[c + 2] + 0.2f * gb[c + 2]),
                 bf16((v.w - mean) * rstd * gw[c + 3] + 0.2f * gb[c + 3]) };
    *(bf16x4*)(Xn + ((size_t)b * NB_S + srow) * 1024 + c) = o;
  }
}

// ---------------- launch ----------------
extern "C" void kernel_launch(void* const* d_in, const int* in_sizes, int n_in,
                              void* d_out, int out_size, void* d_ws, size_t ws_size,
                              hipStream_t stream) {
  const float* inputs = (const float*)d_in[0];
  const float* amask  = (const float*)d_in[1];
  const int*   tok    = (const int*)d_in[2];
  const float* Wq = (const float*)d_in[3];
  const float* Wk = (const float*)d_in[4];
  const float* Wv = (const float*)d_in[5];
  const float* Wo = (const float*)d_in[6];
  const float* lq1 = (const float*)d_in[7];
  const float* lq2 = (const float*)d_in[8];
  const float* lk1 = (const float*)d_in[9];
  const float* lk2 = (const float*)d_in[10];
  const float* gw = (const float*)d_in[11];
  const float* gb = (const float*)d_in[12];
  float* out = (float*)d_out;
  char* ws = (char*)d_ws;

  bf16* Xbf = (bf16*)(ws + 0);
  bf16* Wqb = (bf16*)(ws + 8388608);       // Wqb||Wkb contiguous -> fused QK gemm
  bf16* Wkb = (bf16*)(ws + 12582912);
  bf16* Wvb = (bf16*)(ws + 16777216);      // dead after V-proj gemm
  float* X  = (float*)(ws + 0);            // aliases Xbf/Wqb/Wkb (dead by attn)
  float* combo = (float*)(ws + 16777216);  // aliases Wvb (written after V-proj)
  bf16* Qb  = (bf16*)(ws + 18874368);
  bf16* Xn  = (bf16*)(ws + 18874368);      // aliases Qb (dead after attn)
  bf16* Kb  = (bf16*)(ws + 35651584);
  bf16* Vtb = (bf16*)(ws + 52428800);
  bf16* Wob = (bf16*)(ws + 60817408);
  float* lam = (float*)(ws + 62914560);
  float* gnp = (float*)(ws + 62914816);

  const float QSCALE = 0.125f * 1.44269504088896340736f;  // 1/sqrt(D) * log2(e)

  cvt_kernel<<<4096, 256, 0, stream>>>(inputs, Xbf, 1048576);
  cvt_kernel<<<2048, 256, 0, stream>>>(Wq, Wqb, 524288);
  cvt_kernel<<<2048, 256, 0, stream>>>(Wk, Wkb, 524288);
  cvt_kernel<<<1024, 256, 0, stream>>>(Wv, Wvb, 262144);
  cvt_kernel<<<1024, 256, 0, stream>>>(Wo, Wob, 262144);
  lam_kernel<<<1, 64, 0, stream>>>(lq1, lq2, lk1, lk2, lam);

  // fused Q+K projection: B = Wqb||Wkb (N=4096)
  gemm_bt<0><<<dim3(32, 32), 256, 0, stream>>>(Xbf, Wqb, Qb, Kb, nullptr, 1024, QSCALE);
  gemm_bt<1><<<dim3(32, 8), 256, 0, stream>>>(Xbf, Wvb, Vtb, nullptr, nullptr, 1024, 1.0f);

  combo_kernel<<<256, 256, 0, stream>>>(tok, amask, combo);

  attn_kernel<<<1024, 256, 0, stream>>>(Qb, Kb, Vtb, tok, combo, lam, X);

  gn_part<<<256, 256, 0, stream>>>(X, gnp);
  gn_apply<<<256, 256, 0, stream>>>(X, gnp, gw, gb, Xn);

  gemm_bt<2><<<dim3(32, 8), 256, 0, stream>>>(Xn, Wob, nullptr, nullptr, out, 1024, 1.0f);
}